// Round 8
// baseline (242.929 us; speedup 1.0000x reference)
//
#include <hip/hip_runtime.h>

#define B 8
#define N 2048
#define FIN 10
#define D 128
#define ALPHA 0.02f
#define BR 32     // rows per block, k_proj
#define TI 32     // rows per block, k_attn
#define JC 64     // j-chunk, k_attn
#define NCH (N / JC)               // 32 chunks
#define NBLK_ATTN ((N / TI) * B)   // 512

// LDS arena layout (bytes)
#define WHT_OFF 0                   // 3 x 16384
#define ADJ_OFF 49152               // 3 x 8192
#define E2_OFF  73728               // 3 x 256
#define ARENA_SZ 74496              // epilogue overlays obuf[8][16][132] f32 = 67584

typedef short bf8 __attribute__((ext_vector_type(8)));   // 8 bf16 in 4 VGPRs
typedef float f32x4 __attribute__((ext_vector_type(4)));

__device__ __forceinline__ float lrelu(float x) { return x >= 0.f ? x : ALPHA * x; }

__device__ __forceinline__ short f2b(float f) {
    unsigned u = __float_as_uint(f);
    return (short)((u + 0x7fffu + ((u >> 16) & 1u)) >> 16);
}

__device__ __forceinline__ float b2f(short s) {
    return __uint_as_float(((unsigned)(unsigned short)s) << 16);
}

__device__ __forceinline__ unsigned enc_key(float v) {
    unsigned b = __float_as_uint(v);
    return (b & 0x80000000u) ? ~b : (b | 0x80000000u);
}
__device__ __forceinline__ float dec_key(unsigned k) {
    unsigned b = (k & 0x80000000u) ? (k & 0x7fffffffu) : ~k;
    return __uint_as_float(b);
}

// async global->LDS DMA: no destination register -> scheduler cannot sink it;
// ordered purely by counted vmcnt (T3/T4, proven working in v7b round 7).
__device__ __forceinline__ void dma16(const void* g, void* l) {
    __builtin_amdgcn_global_load_lds(
        (const __attribute__((address_space(1))) void*)g,
        (__attribute__((address_space(3))) void*)l, 16, 0, 0);
}
__device__ __forceinline__ void dma4(const void* g, void* l) {
    __builtin_amdgcn_global_load_lds(
        (const __attribute__((address_space(1))) void*)g,
        (__attribute__((address_space(3))) void*)l, 4, 0, 0);
}

// ---------------------------------------------------------------------------
// k_proj: x = lrelu(LN(h@W1^T+b1)) [bf16] ; Wh = x@Wg^T+bg via MFMA (fp32 acc);
// emits WhT bf16 [d][j] + e1,e2 fp32. Also zero-inits pooled + completion cnt.
// Block = 32 rows, 256 threads (4 waves). Grid = B*N/32 = 512.  (unchanged)
// ---------------------------------------------------------------------------
__global__ __launch_bounds__(256) void k_proj(
    const float* __restrict__ h, const float* __restrict__ W1, const float* __restrict__ b1,
    const float* __restrict__ Wg, const float* __restrict__ bg,
    const float* __restrict__ a1, const float* __restrict__ a2,
    unsigned short* __restrict__ WhT, float* __restrict__ e1g, float* __restrict__ e2g,
    unsigned* __restrict__ pooled, unsigned* __restrict__ cnt)
{
    __shared__ __align__(16) short xep_lds[32 * 136];
    __shared__ __align__(16) short wg_lds[D * 136];
    __shared__ float W1_lds[D * 11];
    __shared__ float h_lds[BR * FIN];
    __shared__ float ep1[2][BR], ep2[2][BR];

    const int t = threadIdx.x;
    const int r0 = blockIdx.x * BR;
    const int bb = r0 >> 11;
    const int jloc = r0 & (N - 1);

    // zero-init pooled (blocks 0..7) and counter (block 0)
    if (blockIdx.x < B && t < D) pooled[blockIdx.x * D + t] = 0u;
    if (blockIdx.x == 0 && t == 128) *cnt = 0u;

    for (int idx = t; idx < D * FIN; idx += 256)
        W1_lds[(idx / FIN) * 11 + (idx % FIN)] = W1[idx];
    for (int idx = t; idx < BR * FIN; idx += 256)
        h_lds[idx] = h[(size_t)r0 * FIN + idx];
    __syncthreads();

    // stage Wg -> bf16 LDS [dout][din]
    {
        const int dr = t >> 4;
        const int j8 = t & 15;
        #pragma unroll
        for (int pass = 0; pass < 8; pass++) {
            int dd = pass * 16 + dr;
            float4 f0 = *(const float4*)&Wg[dd * D + j8 * 8];
            float4 f1 = *(const float4*)&Wg[dd * D + j8 * 8 + 4];
            bf8 v;
            v[0] = f2b(f0.x); v[1] = f2b(f0.y); v[2] = f2b(f0.z); v[3] = f2b(f0.w);
            v[4] = f2b(f1.x); v[5] = f2b(f1.y); v[6] = f2b(f1.z); v[7] = f2b(f1.w);
            *(bf8*)&wg_lds[dd * 136 + j8 * 8] = v;
        }
    }

    // phase 1: fc1 + LN + lrelu, one row per wave iteration
    const int w = t >> 6, lane = t & 63;
    {
        float b1v0 = b1[lane], b1v1 = b1[lane + 64];
        for (int i = 0; i < 8; i++) {
            int r = w * 8 + i;
            float s0 = b1v0, s1 = b1v1;
            const float* hr = &h_lds[r * FIN];
            #pragma unroll
            for (int k = 0; k < FIN; k++) {
                float hv = hr[k];
                s0 += hv * W1_lds[lane * 11 + k];
                s1 += hv * W1_lds[(lane + 64) * 11 + k];
            }
            float sm = s0 + s1, sq = s0 * s0 + s1 * s1;
            #pragma unroll
            for (int m = 1; m <= 32; m <<= 1) { sm += __shfl_xor(sm, m); sq += __shfl_xor(sq, m); }
            float mean = sm * (1.f / D);
            float var  = sq * (1.f / D) - mean * mean;
            float rs = rsqrtf(var + 1e-5f);
            xep_lds[r * 136 + lane]      = f2b(lrelu((s0 - mean) * rs));
            xep_lds[r * 136 + lane + 64] = f2b(lrelu((s1 - mean) * rs));
        }
    }
    __syncthreads();

    // phase 2: MFMA  Wh[32][128] = x @ Wg^T
    const int l15 = lane & 15, q = lane >> 4;
    const int mw = w & 1, np = w >> 1;
    f32x4 acc[4];
    #pragma unroll
    for (int nt = 0; nt < 4; nt++)
        #pragma unroll
        for (int r = 0; r < 4; r++) acc[nt][r] = 0.f;

    #pragma unroll
    for (int ks = 0; ks < 4; ks++) {
        bf8 av = *(const bf8*)&xep_lds[(mw * 16 + l15) * 136 + ks * 32 + q * 8];
        #pragma unroll
        for (int nt = 0; nt < 4; nt++) {
            bf8 bv = *(const bf8*)&wg_lds[((np * 4 + nt) * 16 + l15) * 136 + ks * 32 + q * 8];
            acc[nt] = __builtin_amdgcn_mfma_f32_16x16x32_bf16(av, bv, acc[nt], 0, 0, 0);
        }
    }

    // epilogue: +bg, e1/e2 partials
    float e1p[4] = {0.f, 0.f, 0.f, 0.f}, e2p[4] = {0.f, 0.f, 0.f, 0.f};
    #pragma unroll
    for (int nt = 0; nt < 4; nt++) {
        int col = (np * 4 + nt) * 16 + l15;
        float bgv = bg[col], a1v = a1[col], a2v = a2[col];
        #pragma unroll
        for (int r = 0; r < 4; r++) {
            float v = acc[nt][r] + bgv;
            acc[nt][r] = v;
            e1p[r] += v * a1v;
            e2p[r] += v * a2v;
        }
    }
    #pragma unroll
    for (int m = 1; m <= 8; m <<= 1) {
        #pragma unroll
        for (int r = 0; r < 4; r++) { e1p[r] += __shfl_xor(e1p[r], m); e2p[r] += __shfl_xor(e2p[r], m); }
    }
    if (l15 == 0) {
        #pragma unroll
        for (int r = 0; r < 4; r++) {
            ep1[np][mw * 16 + q * 4 + r] = e1p[r];
            ep2[np][mw * 16 + q * 4 + r] = e2p[r];
        }
    }
    __syncthreads();
    if (t < BR) {
        e1g[r0 + t] = ep1[0][t] + ep1[1][t];
        e2g[r0 + t] = ep2[0][t] + ep2[1][t];
    }
    #pragma unroll
    for (int nt = 0; nt < 4; nt++) {
        int col = (np * 4 + nt) * 16 + l15;
        #pragma unroll
        for (int r = 0; r < 4; r++)
            xep_lds[col * 36 + mw * 16 + q * 4 + r] = f2b(acc[nt][r]);
    }
    __syncthreads();
    {
        const int col = t >> 1, jh = (t & 1) * 16;
        unsigned short* dst = WhT + ((size_t)(bb * D + col)) * N + jloc + jh;
        #pragma unroll
        for (int i2 = 0; i2 < 4; i2++)
            *(uint2*)(dst + i2 * 4) = *(const uint2*)&xep_lds[col * 36 + jh + i2 * 4];
    }
}

// ---------------------------------------------------------------------------
// k_attn v8: in-lane P + O^T MFMA + triple-buffered DMA staging.
//  - B-fragment of mfma IS the P row-fragment a lane can compute in-lane
//    (P[i=l15][j=q*8+e]); A-fragment = WhT rows from DMA-staged LDS.
//    -> NO pT LDS, NO producer/consumer barrier, ONE barrier per chunk.
//  - Wave w: i-block=w>>2, k-slice=w&1, chunk-parity=(w>>1)&1. Every P value
//    computed by exactly one lane (no redundancy). acc = 8 d-tiles (32 VGPR);
//    O[i][d] partials over disjoint j-sets reduced via LDS at the end.
//  - Staging: JC=64, K=3 buffers (one barrier/chunk is safe: writer targets
//    buf[(c+1)%3], concurrent readers hold buf[c%3] and buf[(c-1)%3]).
//    4 DMA ops/wave/chunk; steady-state wait vmcnt(4) = full-chunk distance.
//  - whT and adj XOR-swizzled (pre-swizzled source + swizzled read, rule 21).
//  - Epilogue overlays obuf[8][16][132] f32 onto the dead staging arena.
// Block = 32 i-rows, 512 threads (8 waves). Grid = (64, 8). LDS 75 KB -> 2/CU.
// ---------------------------------------------------------------------------
__global__ __launch_bounds__(512, 4) void k_attn(
    const int* __restrict__ adj, const unsigned short* __restrict__ WhT,
    const float* __restrict__ e1g, const float* __restrict__ e2g,
    unsigned* __restrict__ pooled, unsigned* __restrict__ cnt,
    const float* __restrict__ W2, const float* __restrict__ b2,
    float* __restrict__ out)
{
    __shared__ __align__(16) char arena[ARENA_SZ];
    __shared__ float lp[8][16];
    __shared__ unsigned maxd[D];
    __shared__ int finalflag;

    const int t = threadIdx.x;
    const int b = blockIdx.y;
    const int i0 = blockIdx.x * TI;

    const int w = t >> 6, lane = t & 63;
    const int l15 = lane & 15, q = lane >> 4;

    const int ib  = w >> 2;          // i-block (0/1)
    const int g   = w & 3;
    const int ksw = g & 1;           // k-slice within chunk (0/1)
    const int par = g >> 1;          // chunk parity this wave computes
    const int prow = ib * 16 + l15;  // P row (0..31)

    if (t < D) maxd[t] = 0u;

    const float e1v = e1g[b * N + i0 + prow];
    const unsigned short* WhTb = WhT + (size_t)b * D * N;
    const int* adjb = adj + ((size_t)b * N + i0) * N;
    const float* e2b = e2g + (size_t)b * N;

    f32x4 acc[8];
    #pragma unroll
    for (int db = 0; db < 8; db++)
        #pragma unroll
        for (int r = 0; r < 4; r++) acc[db][r] = 0.f;
    float ls = 0.f;

    // stage chunk jcn into buffer buf: 4 DMA ops per wave (uniform)
    auto stage = [&](int jcn, int buf) {
        // whT: 2 ops; dest linear, source pre-swizzled (scol)
        #pragma unroll
        for (int p = 0; p < 2; p++) {
            int x = p * 8192 + w * 1024 + lane * 16;     // 0..16383
            int rowx = x >> 7;                            // 128 B per d-row
            int scol = (x & 127) ^ ((rowx & 7) << 4);
            dma16((const char*)WhTb + (size_t)rowx * (N * 2) + jcn * (JC * 2) + scol,
                  arena + WHT_OFF + buf * 16384 + x);
        }
        // adj: 1 op; same both-sides swizzle
        {
            int y = w * 1024 + lane * 16;                 // 0..8191
            int rowy = y >> 8;                            // 256 B per i-row
            int scola = (y & 255) ^ ((rowy & 7) << 4);
            dma16((const char*)adjb + (size_t)rowy * (N * 4) + jcn * (JC * 4) + scola,
                  arena + ADJ_OFF + buf * 8192 + y);
        }
        // e2: 1 op (redundant identical writes across waves -> benign)
        dma4((const char*)e2b + jcn * (JC * 4) + lane * 4,
             arena + E2_OFF + buf * 256 + lane * 4);
    };

    // prologue: chunk 0 -> buf 0
    stage(0, 0);

    int cur = 0, nxt = 1;
    for (int jc = 0; jc < NCH; jc++) {
        const int jn = (jc + 1 < NCH) ? jc + 1 : 0;   // wrap (harmless)
        stage(jn, nxt);

        // chunk jc's 4 ops (issued last iter) landed once <=4 remain in flight
        asm volatile("s_waitcnt vmcnt(4) lgkmcnt(0)" ::: "memory");
        __builtin_amdgcn_sched_barrier(0);
        __builtin_amdgcn_s_barrier();     // all waves' chunk-jc data visible

        if ((jc & 1) == par) {
            // in-lane P fragment: row prow, j = jc*64 + ksw*32 + q*8 + e
            const char* abase = arena + ADJ_OFF + cur * 8192 + prow * 256;
            const int acol = ksw * 128 + q * 32;
            const int sw = (prow & 7) << 4;
            int4 av0 = *(const int4*)(abase + (acol ^ sw));
            int4 av1 = *(const int4*)(abase + ((acol + 16) ^ sw));
            const char* ebase = arena + E2_OFF + cur * 256 + ksw * 128 + q * 32;
            float4 ev0 = *(const float4*)ebase;
            float4 ev1 = *(const float4*)(ebase + 16);

            bf8 pa;
            pa[0] = f2b(av0.x ? __expf(lrelu(e1v + ev0.x)) : 0.f);
            pa[1] = f2b(av0.y ? __expf(lrelu(e1v + ev0.y)) : 0.f);
            pa[2] = f2b(av0.z ? __expf(lrelu(e1v + ev0.z)) : 0.f);
            pa[3] = f2b(av0.w ? __expf(lrelu(e1v + ev0.w)) : 0.f);
            pa[4] = f2b(av1.x ? __expf(lrelu(e1v + ev1.x)) : 0.f);
            pa[5] = f2b(av1.y ? __expf(lrelu(e1v + ev1.y)) : 0.f);
            pa[6] = f2b(av1.z ? __expf(lrelu(e1v + ev1.z)) : 0.f);
            pa[7] = f2b(av1.w ? __expf(lrelu(e1v + ev1.w)) : 0.f);
            ls += b2f(pa[0]) + b2f(pa[1]) + b2f(pa[2]) + b2f(pa[3])
                + b2f(pa[4]) + b2f(pa[5]) + b2f(pa[6]) + b2f(pa[7]);

            // A-fragments: WhT rows (swizzled read); O^T MFMA, acc per d-tile
            __builtin_amdgcn_s_setprio(1);
            #pragma unroll
            for (int db = 0; db < 8; db++) {
                int brow = db * 16 + l15;
                const bf8* bp = (const bf8*)(arena + WHT_OFF + cur * 16384
                                 + brow * 128
                                 + ((ksw * 64 + q * 16) ^ ((brow & 7) << 4)));
                acc[db] = __builtin_amdgcn_mfma_f32_16x16x32_bf16(*bp, pa, acc[db], 0, 0, 0);
            }
            __builtin_amdgcn_s_setprio(0);
        }

        cur = nxt;
        nxt = (nxt + 1 == 3) ? 0 : nxt + 1;
    }

    // drain wrap DMAs before overlaying the arena with O partials
    asm volatile("s_waitcnt vmcnt(0) lgkmcnt(0)" ::: "memory");
    __syncthreads();

    // row-sum: reduce over q (xor 16 = q bit0, xor 32 = q bit1), publish
    ls += __shfl_xor(ls, 16);
    ls += __shfl_xor(ls, 32);
    if (lane < 16) lp[w][lane] = ls;

    // O^T partials -> obuf slot w: acc[db][r] = O[i=ib*16+l15][d=db*16+q*4+r]
    {
        float* obuf = (float*)arena;            // [8][16][132]
        float* orow = obuf + w * (16 * 132) + l15 * 132;
        #pragma unroll
        for (int db = 0; db < 8; db++)
            *(f32x4*)(orow + db * 16 + q * 4) = acc[db];
    }
    __syncthreads();

    // combine 4 wave-partials per i-block; /l; LN per row; lrelu; per-d max
    {
        const float* obuf = (const float*)arena;
        const int ri = t >> 4;          // 0..31 row in tile
        const int c  = t & 15;          // 16 threads per row
        const int ibt = ri >> 4, rloc = ri & 15;
        const int dbase = c * 8;
        float lsum = lp[ibt * 4 + 0][rloc] + lp[ibt * 4 + 1][rloc]
                   + lp[ibt * 4 + 2][rloc] + lp[ibt * 4 + 3][rloc];
        float rinv = 1.f / lsum;
        float o[8];
        #pragma unroll
        for (int k = 0; k < 8; k += 4) {
            float4 s0 = *(const float4*)(obuf + (ibt * 4 + 0) * 2112 + rloc * 132 + dbase + k);
            float4 s1 = *(const float4*)(obuf + (ibt * 4 + 1) * 2112 + rloc * 132 + dbase + k);
            float4 s2 = *(const float4*)(obuf + (ibt * 4 + 2) * 2112 + rloc * 132 + dbase + k);
            float4 s3 = *(const float4*)(obuf + (ibt * 4 + 3) * 2112 + rloc * 132 + dbase + k);
            o[k + 0] = (s0.x + s1.x + s2.x + s3.x) * rinv;
            o[k + 1] = (s0.y + s1.y + s2.y + s3.y) * rinv;
            o[k + 2] = (s0.z + s1.z + s2.z + s3.z) * rinv;
            o[k + 3] = (s0.w + s1.w + s2.w + s3.w) * rinv;
        }
        float sm = 0.f, sq = 0.f;
        #pragma unroll
        for (int k = 0; k < 8; k++) { sm += o[k]; sq += o[k] * o[k]; }
        #pragma unroll
        for (int m = 1; m <= 8; m <<= 1) { sm += __shfl_xor(sm, m); sq += __shfl_xor(sq, m); }
        float mean = sm * (1.f / D);
        float var  = sq * (1.f / D) - mean * mean;
        float rs = rsqrtf(var + 1e-5f);
        #pragma unroll
        for (int k = 0; k < 8; k++) {
            float v = lrelu((o[k] - mean) * rs);
            atomicMax(&maxd[dbase + k], enc_key(v));
        }
    }
    __syncthreads();
    if (t < D) atomicMax(&pooled[b * D + t], maxd[t]);
    __syncthreads();           // all this block's atomics drained

    // completion counter; last block does final 128->2 matmul + log_softmax
    if (t == 0) {
        __threadfence();
        unsigned old = atomicAdd(cnt, 1u);
        finalflag = (old == NBLK_ATTN - 1) ? 1 : 0;
    }
    __syncthreads();
    if (finalflag && t < 256) {
        const int fb = t >> 5;
        const int fq = t & 31;
        float s0 = 0.f, s1 = 0.f;
        #pragma unroll
        for (int m = 0; m < 4; m++) {
            int dd = fq + 32 * m;
            unsigned key = __hip_atomic_load(&pooled[fb * D + dd], __ATOMIC_RELAXED,
                                             __HIP_MEMORY_SCOPE_AGENT);
            float v = dec_key(key);
            s0 += v * W2[dd];
            s1 += v * W2[D + dd];
        }
        #pragma unroll
        for (int m = 1; m <= 16; m <<= 1) { s0 += __shfl_xor(s0, m); s1 += __shfl_xor(s1, m); }
        if (fq == 0) {
            float o0 = s0 + b2[0], o1 = s1 + b2[1];
            float mxv = fmaxf(o0, o1);
            float ls2 = logf(__expf(o0 - mxv) + __expf(o1 - mxv));
            out[fb * 2 + 0] = o0 - mxv - ls2;
            out[fb * 2 + 1] = o1 - mxv - ls2;
        }
    }
}

extern "C" void kernel_launch(void* const* d_in, const int* in_sizes, int n_in,
                              void* d_out, int out_size, void* d_ws, size_t ws_size,
                              hipStream_t stream) {
    const float* h   = (const float*)d_in[0];
    const int*   adj = (const int*)d_in[1];
    const float* W1  = (const float*)d_in[2];
    const float* b1  = (const float*)d_in[3];
    const float* Wg  = (const float*)d_in[4];
    const float* bg  = (const float*)d_in[5];
    const float* a1  = (const float*)d_in[6];
    const float* a2  = (const float*)d_in[7];
    const float* W2  = (const float*)d_in[8];
    const float* b2  = (const float*)d_in[9];
    float* out = (float*)d_out;

    unsigned short* WhT = (unsigned short*)d_ws;                       // B*D*N bf16
    float* e1g = (float*)((char*)d_ws + (size_t)B * D * N * 2);        // B*N f32
    float* e2g = e1g + (size_t)B * N;                                  // B*N f32
    unsigned* pooled = (unsigned*)(e2g + (size_t)B * N);               // B*D u32
    unsigned* cnt = pooled + (size_t)B * D;                            // 1 u32

    k_proj<<<(B * N) / BR, 256, 0, stream>>>(h, W1, b1, Wg, bg, a1, a2,
                                             WhT, e1g, e2g, pooled, cnt);
    k_attn<<<dim3(N / TI, B), 512, 0, stream>>>(adj, WhT, e1g, e2g, pooled, cnt,
                                                W2, b2, out);
}